// Round 9
// baseline (165.858 us; speedup 1.0000x reference)
//
#include <hip/hip_runtime.h>

#define D_MODEL 64
#define SEQ     4096
#define BATCH   256
#define NSIG    128
#define CSTEP   64
#define NCHUNK  (SEQ / CSTEP)   // 64
#define NGRP    (SEQ / 8)       // 512 groups of 8 steps

constexpr float PHI_F     = 1.61803398874989484820f;
constexpr float TWO_PI_F  = 6.28318530717958647692f;
constexpr float INV2PI_F  = 0.15915494309189533577f;
constexpr float MAGIC_F   = 3072.0f;            // quantizes at ulp 2^-12 = 1 LUT bin
constexpr float FLOORB_F  = 0.0001220703125f;   // 2^-13: RNE(y - 2^-13) at 2^-12 grid == floor

// One block (512 threads = 8 waves) per batch row (256 blocks).
// wave 0 (prio 3): serial 4096-step scan (lane = dim). Chain per step:
//   pk_fma -> pk_add(+-3072 magic quantize) -> add -> cos/sin.
// waves 1-7 (prio 0): loaders — ~10 steps each per chunk, one latency round.
// 4-slot LDS ring, loaders 3 chunks ahead; float2 plane layout (conflict-free).
__global__ __launch_bounds__(512, 1)
void rin_scan_kernel(const int* __restrict__ ids,
                     const float* __restrict__ emb,   // (50257, 128) f32
                     const float* __restrict__ pw,    // (128, 128) f32
                     const float* __restrict__ pb,    // (128,) f32
                     float* __restrict__ out)         // (256, 128) f32
{
  __shared__ int    lds_ids[SEQ];                // 16 KB
  __shared__ float2 ring[4][CSTEP][D_MODEL];     // 128 KB: (r4, C) per [slot][step][lane]
  __shared__ float  lds_h[2 * D_MODEL];

  const int tid  = threadIdx.x;
  const int wave = tid >> 6;
  const int lane = tid & 63;
  const int b    = blockIdx.x;

  // ---- stage token ids (coalesced int4, all 512 threads) ----
  {
    const int4* src = (const int4*)(ids + b * SEQ);
    int4* dst = (int4*)lds_ids;
    #pragma unroll
    for (int i = 0; i < SEQ / 4 / 512; ++i)      // 2 iters
      dst[tid + i * 512] = src[tid + i * 512];
  }
  __syncthreads();

  // wave 0 owns the serial chain: always win issue arbitration on its SIMD.
  if (wave == 0) __builtin_amdgcn_s_setprio(3);
  else           __builtin_amdgcn_s_setprio(0);

  float hr = 0.0f, hi = 0.0f;

  // ---- loader: stage chunk c into ring slot s (waves 1-7, ~10 units each) ----
  auto stage = [&](int c, int s) {
    float wv[10], bv[10];
    #pragma unroll
    for (int k = 0; k < 10; ++k) {
      int i = 7 * k + (wave - 1); i = (i < CSTEP) ? i : (CSTEP - 1);
      int t = c * CSTEP + i;
      int id = lds_ids[t];                       // wave-uniform
      const float* row = emb + (size_t)id * (2 * D_MODEL);
      wv[k] = row[lane];
      bv[k] = row[D_MODEL + lane];
    }
    #pragma unroll
    for (int k = 0; k < 10; ++k) {
      int i = 7 * k + (wave - 1); i = (i < CSTEP) ? i : (CSTEP - 1);
      int t = c * CSTEP + i;
      float pf  = (float)t * PHI_F;
      float n   = floorf(pf * INV2PI_F);
      float tp  = fmaf(-n, TWO_PI_F, pf);        // fmod(t*PHI, 2pi)
      float tpr = tp * INV2PI_F;                 // revolutions
      float r4  = __builtin_amdgcn_rcpf(1.0f + fabsf(wv[k])) * INV2PI_F;
      float C   = fmaf(bv[k], INV2PI_F, tpr) - FLOORB_F;
      ring[s][i][lane] = make_float2(r4, C);     // duplicate writes at clamp: same data
    }
  };

  // ---- compute helpers (wave 0); g = global group index 0..NGRP-1 ----
  auto P = [&](int g, float2* dst) {
    int gg = (g < NGRP) ? g : (NGRP - 1);
    const float2* base = &ring[(gg >> 3) & 3][(gg & 7) * 8][0];  // single vaddr
    #pragma unroll
    for (int u = 0; u < 8; ++u)
      dst[u] = base[u * D_MODEL + lane];         // imm offsets off one base
  };
  auto S = [&](const float2* F) {
    #pragma unroll
    for (int u = 0; u < 8; ++u) {
      float2 v = F[u];
      // packed-friendly form: z = pk_fma((hr,hi),(r4,r4),(C,C)); q = z + (M,-M)
      float z1 = fmaf(hr, v.x, v.y);
      float z2 = fmaf(hi, v.x, v.y);
      float q1 = z1 + MAGIC_F;                   // RNE at 2^-12 grid => floor (bias in C)
      float q2 = z2 - MAGIC_F;
      float f  = q1 + q2;                        // exact: magics cancel, |f| < 4
      hr = __builtin_amdgcn_cosf(f);             // HW range reduction covers |f| <= 4
      hi = __builtin_amdgcn_sinf(f);
    }
  };

  // ---- pipeline fill: loaders stage chunks 0..2 ----
  if (wave > 0) { stage(0, 0); stage(1, 1); stage(2, 2); }
  __syncthreads();

  float2 A[8], B[8];
  if (wave == 0) P(0, A);

  for (int c = 0; c < NCHUNK; ++c) {
    if (wave > 0) {
      if (c + 3 < NCHUNK) stage(c + 3, (c + 3) & 3);
    } else {
      const int g0 = c * 8;
      P(g0 + 1, B); S(A);
      P(g0 + 2, A); S(B);
      P(g0 + 3, B); S(A);
      P(g0 + 4, A); S(B);
      P(g0 + 5, B); S(A);
      P(g0 + 6, A); S(B);
      P(g0 + 7, B); S(A);
      P(g0 + 8, A); S(B);    // cross-chunk prefetch (slot (c+1)&3, staged >= 1 barrier ago)
    }
    __syncthreads();
  }

  // ---- projection: out[b, j] = sum_k h[k] * pw[j, k] + pb[j] ----
  if (wave == 0) {
    lds_h[lane] = hr;
    lds_h[D_MODEL + lane] = hi;
  }
  __syncthreads();
  if (tid < NSIG) {
    int j = tid;
    const float4* wrow = (const float4*)(pw + j * NSIG);
    float acc = pb[j];
    #pragma unroll
    for (int k = 0; k < NSIG / 4; ++k) {
      float4 wvv = wrow[k];
      float4 hv  = *(const float4*)&lds_h[k * 4];
      acc = fmaf(hv.x, wvv.x, acc);
      acc = fmaf(hv.y, wvv.y, acc);
      acc = fmaf(hv.z, wvv.z, acc);
      acc = fmaf(hv.w, wvv.w, acc);
    }
    out[b * NSIG + j] = acc;
  }
}

extern "C" void kernel_launch(void* const* d_in, const int* in_sizes, int n_in,
                              void* d_out, int out_size, void* d_ws, size_t ws_size,
                              hipStream_t stream) {
  const int*   ids = (const int*)d_in[0];
  const float* emb = (const float*)d_in[1];
  const float* pw  = (const float*)d_in[2];
  const float* pb  = (const float*)d_in[3];
  float*       out = (float*)d_out;

  rin_scan_kernel<<<dim3(BATCH), dim3(512), 0, stream>>>(ids, emb, pw, pb, out);
}

// Round 10
// 163.173 us; speedup vs baseline: 1.0165x; 1.0165x over previous
//
#include <hip/hip_runtime.h>

#define D_MODEL 64
#define SEQ     4096
#define BATCH   256
#define NSIG    128
#define CSTEP   64
#define NCHUNK  (SEQ / CSTEP)   // 64
#define NGRP    (SEQ / 8)       // 512 groups of 8 steps

constexpr float PHI_F     = 1.61803398874989484820f;
constexpr float TWO_PI_F  = 6.28318530717958647692f;
constexpr float INV2PI_F  = 0.15915494309189533577f;
constexpr float MAGIC_F   = 3072.0f;            // addend magnitude => fma result ulp 2^-12 = 1 LUT bin
constexpr float DMAGIC_F  = 6144.0f;            // C2 = C1 - 6144 (exact on the 2^-12 grid)
constexpr float FLOORB_F  = 0.0001220703125f;   // 2^-13 half-bin bias: RNE == floor

// One block (512 threads = 8 waves) per batch row (256 blocks).
// wave 0 (prio 3): serial 4096-step scan (lane = dim). Chain per step:
//   q1 = fma(hr, s, C1)   <- FMA's single RNE at ulp 2^-12 IS the floor quantize
//   q2 = fma(hi, s, C2)   (parallel; C2 = C1 - 6144 computed off-chain)
//   f  = q1 + q2          (magics cancel exactly)
//   hr = cos(f), hi = sin(f)
//   => 2 VALU links + trans pair on the critical path (was 3 + trans).
// waves 1-7 (prio 0): loaders — ~10 steps each per chunk, one latency round.
// 4-slot LDS ring, loaders 3 chunks ahead; float2 plane layout (conflict-free).
__global__ __launch_bounds__(512, 1)
void rin_scan_kernel(const int* __restrict__ ids,
                     const float* __restrict__ emb,   // (50257, 128) f32
                     const float* __restrict__ pw,    // (128, 128) f32
                     const float* __restrict__ pb,    // (128,) f32
                     float* __restrict__ out)         // (256, 128) f32
{
  __shared__ int    lds_ids[SEQ];                // 16 KB
  __shared__ float2 ring[4][CSTEP][D_MODEL];     // 128 KB: (r4, C1) per [slot][step][lane]
  __shared__ float  lds_h[2 * D_MODEL];

  const int tid  = threadIdx.x;
  const int wave = tid >> 6;
  const int lane = tid & 63;
  const int b    = blockIdx.x;

  // ---- stage token ids (coalesced int4, all 512 threads) ----
  {
    const int4* src = (const int4*)(ids + b * SEQ);
    int4* dst = (int4*)lds_ids;
    #pragma unroll
    for (int i = 0; i < SEQ / 4 / 512; ++i)      // 2 iters
      dst[tid + i * 512] = src[tid + i * 512];
  }
  __syncthreads();

  if (wave == 0) __builtin_amdgcn_s_setprio(3);
  else           __builtin_amdgcn_s_setprio(0);

  float hr = 0.0f, hi = 0.0f;

  // ---- loader: stage chunk c into ring slot s (waves 1-7, ~10 units each) ----
  auto stage = [&](int c, int s) {
    float wv[10], bv[10];
    #pragma unroll
    for (int k = 0; k < 10; ++k) {
      int i = 7 * k + (wave - 1); i = (i < CSTEP) ? i : (CSTEP - 1);
      int t = c * CSTEP + i;
      int id = lds_ids[t];                       // wave-uniform
      const float* row = emb + (size_t)id * (2 * D_MODEL);
      wv[k] = row[lane];
      bv[k] = row[D_MODEL + lane];
    }
    #pragma unroll
    for (int k = 0; k < 10; ++k) {
      int i = 7 * k + (wave - 1); i = (i < CSTEP) ? i : (CSTEP - 1);
      int t = c * CSTEP + i;
      float pf  = (float)t * PHI_F;
      float n   = floorf(pf * INV2PI_F);
      float tp  = fmaf(-n, TWO_PI_F, pf);        // fmod(t*PHI, 2pi)
      float tpr = tp * INV2PI_F;                 // revolutions
      float r4  = __builtin_amdgcn_rcpf(1.0f + fabsf(wv[k])) * INV2PI_F;
      float C   = fmaf(bv[k], INV2PI_F, tpr) - FLOORB_F;
      float C1  = C + MAGIC_F;                   // pre-rounded to bin grid (<= half-bin shift)
      ring[s][i][lane] = make_float2(r4, C1);    // duplicate writes at clamp: same data
    }
  };

  // ---- compute helpers (wave 0); g = global group index 0..NGRP-1 ----
  auto P = [&](int g, float2* dst) {
    int gg = (g < NGRP) ? g : (NGRP - 1);
    const float2* base = &ring[(gg >> 3) & 3][(gg & 7) * 8][0];
    #pragma unroll
    for (int u = 0; u < 8; ++u)
      dst[u] = base[u * D_MODEL + lane];
  };
  auto S = [&](const float2* F) {
    float c2[8];
    #pragma unroll
    for (int u = 0; u < 8; ++u)                  // off-chain: data prefetched a group ago
      c2[u] = F[u].y - DMAGIC_F;                 // exact (both on 2^-12 grid)
    #pragma unroll
    for (int u = 0; u < 8; ++u) {
      float q1 = fmaf(hr, F[u].x, F[u].y);       // single RNE at bin grid == floor quantize
      float q2 = fmaf(hi, F[u].x, c2[u]);
      float f  = q1 + q2;                        // exact: magics cancel, |f| < 8
      hr = __builtin_amdgcn_cosf(f);             // HW range reduction covers |f| <= 8
      hi = __builtin_amdgcn_sinf(f);
    }
  };

  // ---- pipeline fill: loaders stage chunks 0..2 ----
  if (wave > 0) { stage(0, 0); stage(1, 1); stage(2, 2); }
  __syncthreads();

  float2 A[8], B[8];
  if (wave == 0) P(0, A);

  for (int c = 0; c < NCHUNK; ++c) {
    if (wave > 0) {
      if (c + 3 < NCHUNK) stage(c + 3, (c + 3) & 3);
    } else {
      const int g0 = c * 8;
      P(g0 + 1, B); S(A);
      P(g0 + 2, A); S(B);
      P(g0 + 3, B); S(A);
      P(g0 + 4, A); S(B);
      P(g0 + 5, B); S(A);
      P(g0 + 6, A); S(B);
      P(g0 + 7, B); S(A);
      P(g0 + 8, A); S(B);    // cross-chunk prefetch (slot (c+1)&3, staged >= 1 barrier ago)
    }
    __syncthreads();
  }

  // ---- projection: out[b, j] = sum_k h[k] * pw[j, k] + pb[j] ----
  if (wave == 0) {
    lds_h[lane] = hr;
    lds_h[D_MODEL + lane] = hi;
  }
  __syncthreads();
  if (tid < NSIG) {
    int j = tid;
    const float4* wrow = (const float4*)(pw + j * NSIG);
    float acc = pb[j];
    #pragma unroll
    for (int k = 0; k < NSIG / 4; ++k) {
      float4 wvv = wrow[k];
      float4 hv  = *(const float4*)&lds_h[k * 4];
      acc = fmaf(hv.x, wvv.x, acc);
      acc = fmaf(hv.y, wvv.y, acc);
      acc = fmaf(hv.z, wvv.z, acc);
      acc = fmaf(hv.w, wvv.w, acc);
    }
    out[b * NSIG + j] = acc;
  }
}

extern "C" void kernel_launch(void* const* d_in, const int* in_sizes, int n_in,
                              void* d_out, int out_size, void* d_ws, size_t ws_size,
                              hipStream_t stream) {
  const int*   ids = (const int*)d_in[0];
  const float* emb = (const float*)d_in[1];
  const float* pw  = (const float*)d_in[2];
  const float* pb  = (const float*)d_in[3];
  float*       out = (float*)d_out;

  rin_scan_kernel<<<dim3(BATCH), dim3(512), 0, stream>>>(ids, emb, pw, pb, out);
}